// Round 5
// baseline (378.301 us; speedup 1.0000x reference)
//
#include <hip/hip_runtime.h>
#include <hip/hip_bf16.h>
#include <math.h>

// Problem constants
constexpr int N_NODES = 50000;
constexpr int E_EDGES = 800000;
constexpr int ETOT    = E_EDGES + N_NODES;   // +self loops
constexpr float NEG_SLOPE = 0.2f;
constexpr float NEG_INF   = -3.0e38f;
constexpr int MAXD = 128;   // LDS-cached edges per dst (fallback beyond; random graph max in-deg ~48)

static inline int cdiv(long long a, int b) { return (int)((a + b - 1) / b); }

__device__ inline float leaky(float a) { return a > 0.f ? a : NEG_SLOPE * a; }
__device__ inline float bf2f(unsigned short u) { return __uint_as_float((unsigned)u << 16); }
__device__ inline unsigned short f2bf(float f) {
    __hip_bfloat16 h = __float2bfloat16(f);
    return *reinterpret_cast<unsigned short*>(&h);
}
__device__ inline void edge_sd(const int* __restrict__ ei, int e, int& s, int& d) {
    if (e < E_EDGES) { s = ei[e]; d = ei[E_EDGES + e]; }
    else             { s = e - E_EDGES; d = s; }
}

// ====== GEMM1 + fused att1: h1b[N,128] bf16, als1/ald1[N,4] ======
// 32 rows/block, 4 rows/thread, k-blocked x4 so all LDS reads are b128 (FMA-bound)
__global__ __launch_bounds__(256) void gemm1_kernel(const float* __restrict__ x,
                                                    const float* __restrict__ W,
                                                    const float* __restrict__ as1,
                                                    const float* __restrict__ ad1,
                                                    unsigned short* __restrict__ h1b,
                                                    float* __restrict__ als,
                                                    float* __restrict__ ald) {
    __shared__ float wS[64 * 128];   // 32 KB
    __shared__ float xS[32 * 128];   // 16 KB
    int t = threadIdx.x;
    int row0 = blockIdx.x * 32;
    #pragma unroll
    for (int i = 0; i < 4; ++i) {
        int fi = i * 256 + t;
        int r = fi >> 5, c4 = (fi & 31) * 4;
        int gr = row0 + r;
        float4 v = make_float4(0.f, 0.f, 0.f, 0.f);
        if (gr < N_NODES) v = *(const float4*)&x[(size_t)gr * 128 + c4];
        *(float4*)&xS[r * 128 + c4] = v;
    }
    int rg   = t >> 5;          // row group 0..7 -> rows rg*4..rg*4+3
    int col4 = (t & 31) * 4;    // 0..124
    float4 a0 = make_float4(0.f,0.f,0.f,0.f), a1 = a0, a2 = a0, a3 = a0;
    for (int kk = 0; kk < 128; kk += 64) {
        __syncthreads();
        for (int i = 0; i < 8; ++i) {
            int idx = (i * 256 + t) * 4;
            *(float4*)&wS[idx] = *(const float4*)&W[kk * 128 + idx];
        }
        __syncthreads();
        for (int k4 = 0; k4 < 64; k4 += 4) {
            float4 w0 = *(float4*)&wS[(k4 + 0) * 128 + col4];
            float4 w1 = *(float4*)&wS[(k4 + 1) * 128 + col4];
            float4 w2 = *(float4*)&wS[(k4 + 2) * 128 + col4];
            float4 w3 = *(float4*)&wS[(k4 + 3) * 128 + col4];
            float4 x0 = *(float4*)&xS[(rg * 4 + 0) * 128 + kk + k4];
            float4 x1 = *(float4*)&xS[(rg * 4 + 1) * 128 + kk + k4];
            float4 x2 = *(float4*)&xS[(rg * 4 + 2) * 128 + kk + k4];
            float4 x3 = *(float4*)&xS[(rg * 4 + 3) * 128 + kk + k4];
            a0.x += x0.x*w0.x + x0.y*w1.x + x0.z*w2.x + x0.w*w3.x;
            a0.y += x0.x*w0.y + x0.y*w1.y + x0.z*w2.y + x0.w*w3.y;
            a0.z += x0.x*w0.z + x0.y*w1.z + x0.z*w2.z + x0.w*w3.z;
            a0.w += x0.x*w0.w + x0.y*w1.w + x0.z*w2.w + x0.w*w3.w;
            a1.x += x1.x*w0.x + x1.y*w1.x + x1.z*w2.x + x1.w*w3.x;
            a1.y += x1.x*w0.y + x1.y*w1.y + x1.z*w2.y + x1.w*w3.y;
            a1.z += x1.x*w0.z + x1.y*w1.z + x1.z*w2.z + x1.w*w3.z;
            a1.w += x1.x*w0.w + x1.y*w1.w + x1.z*w2.w + x1.w*w3.w;
            a2.x += x2.x*w0.x + x2.y*w1.x + x2.z*w2.x + x2.w*w3.x;
            a2.y += x2.x*w0.y + x2.y*w1.y + x2.z*w2.y + x2.w*w3.y;
            a2.z += x2.x*w0.z + x2.y*w1.z + x2.z*w2.z + x2.w*w3.z;
            a2.w += x2.x*w0.w + x2.y*w1.w + x2.z*w2.w + x2.w*w3.w;
            a3.x += x3.x*w0.x + x3.y*w1.x + x3.z*w2.x + x3.w*w3.x;
            a3.y += x3.x*w0.y + x3.y*w1.y + x3.z*w2.y + x3.w*w3.y;
            a3.z += x3.x*w0.z + x3.y*w1.z + x3.z*w2.z + x3.w*w3.z;
            a3.w += x3.x*w0.w + x3.y*w1.w + x3.z*w2.w + x3.w*w3.w;
        }
    }
    float s0 = as1[col4], s1 = as1[col4 + 1], s2 = as1[col4 + 2], s3 = as1[col4 + 3];
    float d0 = ad1[col4], d1 = ad1[col4 + 1], d2 = ad1[col4 + 2], d3 = ad1[col4 + 3];
    #pragma unroll
    for (int r = 0; r < 4; ++r) {
        float4 a = (r == 0) ? a0 : (r == 1) ? a1 : (r == 2) ? a2 : a3;
        int n = row0 + rg * 4 + r;
        float ps = a.x * s0 + a.y * s1 + a.z * s2 + a.w * s3;
        float pd = a.x * d0 + a.y * d1 + a.z * d2 + a.w * d3;
        #pragma unroll
        for (int off = 1; off <= 4; off <<= 1) {
            ps += __shfl_xor(ps, off);
            pd += __shfl_xor(pd, off);
        }
        if (n < N_NODES) {
            uint2 packed;
            packed.x = ((unsigned)f2bf(a.y) << 16) | f2bf(a.x);
            packed.y = ((unsigned)f2bf(a.w) << 16) | f2bf(a.z);
            *(uint2*)&h1b[(size_t)n * 128 + col4] = packed;
            if ((t & 7) == 0) {
                int head = (t & 31) >> 3;
                als[n * 4 + head] = ps;
                ald[n * 4 + head] = pd;
            }
        }
    }
}

// ============ attention logits layer2 (from bf16 h2) ============
__global__ __launch_bounds__(256) void att2_kernel(const unsigned short* __restrict__ h2b,
                                                   const float* __restrict__ as,
                                                   const float* __restrict__ ad,
                                                   float* __restrict__ als,
                                                   float* __restrict__ ald) {
    int t = threadIdx.x;
    int n = blockIdx.x * 4 + (t >> 6);
    if (n >= N_NODES) return;
    int lane = t & 63;
    float v = (lane < 40) ? bf2f(h2b[(size_t)n * 40 + lane]) : 0.f;
    float s = (lane < 40) ? v * as[lane] : 0.f;
    float d = (lane < 40) ? v * ad[lane] : 0.f;
    #pragma unroll
    for (int off = 32; off >= 1; off >>= 1) {
        s += __shfl_xor(s, off);
        d += __shfl_xor(d, off);
    }
    if (lane == 0) { als[n] = s; ald[n] = d; }
}

// ================= CSR build =================
__global__ __launch_bounds__(256) void deg_count_kernel(const int* __restrict__ ei,
                                                        int* __restrict__ deg) {
    int e = blockIdx.x * 256 + threadIdx.x;
    if (e >= ETOT) return;
    int d = (e < E_EDGES) ? ei[E_EDGES + e] : (e - E_EDGES);
    atomicAdd(&deg[d], 1);
}

constexpr int SCAN_CHUNK = 512;
constexpr int SCAN_NBLK  = (N_NODES + SCAN_CHUNK - 1) / SCAN_CHUNK;   // 98

__global__ __launch_bounds__(256) void partial_sum_kernel(const int* __restrict__ deg,
                                                          int* __restrict__ part) {
    __shared__ int s[256];
    int b = blockIdx.x, t = threadIdx.x;
    int i0 = b * SCAN_CHUNK + t;
    int v = 0;
    if (i0 < N_NODES) v += deg[i0];
    if (i0 + 256 < N_NODES && (t + 256) < SCAN_CHUNK) v += deg[i0 + 256];
    s[t] = v; __syncthreads();
    for (int off = 128; off; off >>= 1) {
        if (t < off) s[t] += s[t + off];
        __syncthreads();
    }
    if (t == 0) part[b] = s[0];
}

__global__ void scan_part_kernel(int* __restrict__ part) {
    if (threadIdx.x == 0 && blockIdx.x == 0) {
        int acc = 0;
        for (int i = 0; i < SCAN_NBLK; ++i) { int v = part[i]; part[i] = acc; acc += v; }
    }
}

__global__ __launch_bounds__(256) void chunk_scan_kernel(const int* __restrict__ deg,
                                                         const int* __restrict__ part,
                                                         int* __restrict__ row,
                                                         int* __restrict__ cursor) {
    __shared__ int s[256];
    int b = blockIdx.x, t = threadIdx.x;
    int base = b * SCAN_CHUNK;
    int i0 = base + 2 * t, i1 = base + 2 * t + 1;
    int a0 = (i0 < N_NODES) ? deg[i0] : 0;
    int a1 = (i1 < N_NODES) ? deg[i1] : 0;
    s[t] = a0 + a1;
    __syncthreads();
    for (int off = 1; off < 256; off <<= 1) {
        int v = (t >= off) ? s[t - off] : 0;
        __syncthreads();
        s[t] += v;
        __syncthreads();
    }
    int excl = s[t] - (a0 + a1);
    int off0 = part[b] + excl;
    if (i0 < N_NODES) { row[i0] = off0;      cursor[i0] = off0; }
    if (i1 < N_NODES) { row[i1] = off0 + a0; cursor[i1] = off0 + a0; }
    if (b == 0 && t == 0) row[N_NODES] = ETOT;
}

__global__ __launch_bounds__(256) void fill_csr_kernel(const int* __restrict__ ei,
                                                       int* __restrict__ cursor,
                                                       int* __restrict__ csr_src) {
    int e = blockIdx.x * 256 + threadIdx.x;
    if (e >= ETOT) return;
    int s, d; edge_sd(ei, e, s, d);
    int p = atomicAdd(&cursor[d], 1);
    csr_src[p] = s;
}

// ===== layer1 fused: per-dst softmax (LDS-cached weights) + bf16 gather + bias + ELU =====
// one wave per dst; pass B: lane l <-> channels {2l, 2l+1}, head = l>>4; unrolled x4 for MLP
__global__ __launch_bounds__(256) void agg1_kernel(const int* __restrict__ row,
                                                   const int* __restrict__ csr_src,
                                                   const float4* __restrict__ als4,
                                                   const float4* __restrict__ ald4,
                                                   const unsigned short* __restrict__ h1b,
                                                   const float* __restrict__ b1,
                                                   unsigned short* __restrict__ out1b) {
    __shared__ float wbuf[4][MAXD * 4] __attribute__((aligned(16)));
    int wv   = threadIdx.x >> 6;
    int lane = threadIdx.x & 63;
    int d    = blockIdx.x * 4 + wv;           // grid exactly covers N
    int start = row[d], end = row[d + 1], deg = end - start;
    float4 aldd = ald4[d];

    // pass A: alpha -> LDS, per-lane max
    float4 mx = make_float4(NEG_INF, NEG_INF, NEG_INF, NEG_INF);
    for (int j = lane; j < deg; j += 64) {
        int s = csr_src[start + j];
        float4 a = als4[s];
        a.x = leaky(a.x + aldd.x); a.y = leaky(a.y + aldd.y);
        a.z = leaky(a.z + aldd.z); a.w = leaky(a.w + aldd.w);
        if (j < MAXD) *(float4*)&wbuf[wv][j * 4] = a;
        mx.x = fmaxf(mx.x, a.x); mx.y = fmaxf(mx.y, a.y);
        mx.z = fmaxf(mx.z, a.z); mx.w = fmaxf(mx.w, a.w);
    }
    #pragma unroll
    for (int off = 32; off >= 1; off >>= 1) {
        mx.x = fmaxf(mx.x, __shfl_xor(mx.x, off));
        mx.y = fmaxf(mx.y, __shfl_xor(mx.y, off));
        mx.z = fmaxf(mx.z, __shfl_xor(mx.z, off));
        mx.w = fmaxf(mx.w, __shfl_xor(mx.w, off));
    }
    __syncthreads();

    // pass A2: exp in LDS, per-lane sum
    float4 sm = make_float4(0.f, 0.f, 0.f, 0.f);
    for (int j = lane; j < deg; j += 64) {
        float4 a;
        if (j < MAXD) a = *(float4*)&wbuf[wv][j * 4];
        else {
            int s = csr_src[start + j];
            float4 t = als4[s];
            a.x = leaky(t.x + aldd.x); a.y = leaky(t.y + aldd.y);
            a.z = leaky(t.z + aldd.z); a.w = leaky(t.w + aldd.w);
        }
        float4 e;
        e.x = __expf(a.x - mx.x); e.y = __expf(a.y - mx.y);
        e.z = __expf(a.z - mx.z); e.w = __expf(a.w - mx.w);
        if (j < MAXD) *(float4*)&wbuf[wv][j * 4] = e;
        sm.x += e.x; sm.y += e.y; sm.z += e.z; sm.w += e.w;
    }
    #pragma unroll
    for (int off = 32; off >= 1; off >>= 1) {
        sm.x += __shfl_xor(sm.x, off);
        sm.y += __shfl_xor(sm.y, off);
        sm.z += __shfl_xor(sm.z, off);
        sm.w += __shfl_xor(sm.w, off);
    }
    __syncthreads();

    int head = lane >> 4;
    float m_h = (head & 2) ? ((head & 1) ? mx.w : mx.z) : ((head & 1) ? mx.y : mx.x);
    float s_h = (head & 2) ? ((head & 1) ? sm.w : sm.z) : ((head & 1) ? sm.y : sm.x);
    float d_h = (head & 2) ? ((head & 1) ? aldd.w : aldd.z) : ((head & 1) ? aldd.y : aldd.x);
    float inv_h = 1.f / (s_h + 1e-16f);

    auto wgt = [&](int jj, int ss) -> float {
        if (jj < MAXD) return wbuf[wv][jj * 4 + head];
        float4 a = als4[ss];
        float ah = (head & 2) ? ((head & 1) ? a.w : a.z) : ((head & 1) ? a.y : a.x);
        return __expf(leaky(ah + d_h) - m_h);
    };

    // pass B: gather-aggregate (bf16 rows, cached weights), unrolled x4 for latency hiding
    float acc0 = 0.f, acc1 = 0.f;
    int j = 0;
    for (; j + 3 < deg; j += 4) {
        int s0 = csr_src[start + j];
        int s1 = csr_src[start + j + 1];
        int s2 = csr_src[start + j + 2];
        int s3 = csr_src[start + j + 3];
        unsigned hv0 = *(const unsigned*)(h1b + ((size_t)s0 << 7) + 2 * lane);
        unsigned hv1 = *(const unsigned*)(h1b + ((size_t)s1 << 7) + 2 * lane);
        unsigned hv2 = *(const unsigned*)(h1b + ((size_t)s2 << 7) + 2 * lane);
        unsigned hv3 = *(const unsigned*)(h1b + ((size_t)s3 << 7) + 2 * lane);
        float w0 = wgt(j, s0) * inv_h;
        float w1 = wgt(j + 1, s1) * inv_h;
        float w2 = wgt(j + 2, s2) * inv_h;
        float w3 = wgt(j + 3, s3) * inv_h;
        acc0 += __uint_as_float(hv0 << 16) * w0 + __uint_as_float(hv1 << 16) * w1
              + __uint_as_float(hv2 << 16) * w2 + __uint_as_float(hv3 << 16) * w3;
        acc1 += __uint_as_float(hv0 & 0xffff0000u) * w0 + __uint_as_float(hv1 & 0xffff0000u) * w1
              + __uint_as_float(hv2 & 0xffff0000u) * w2 + __uint_as_float(hv3 & 0xffff0000u) * w3;
    }
    for (; j < deg; ++j) {
        int s0 = csr_src[start + j];
        unsigned hv0 = *(const unsigned*)(h1b + ((size_t)s0 << 7) + 2 * lane);
        float w0 = wgt(j, s0) * inv_h;
        acc0 += __uint_as_float(hv0 << 16)         * w0;
        acc1 += __uint_as_float(hv0 & 0xffff0000u) * w0;
    }
    float v0 = acc0 + b1[2 * lane];
    float v1 = acc1 + b1[2 * lane + 1];
    v0 = v0 > 0.f ? v0 : __expf(v0) - 1.f;
    v1 = v1 > 0.f ? v1 : __expf(v1) - 1.f;
    unsigned p = ((unsigned)f2bf(v1) << 16) | f2bf(v0);
    *(unsigned*)&out1b[(size_t)d * 128 + 2 * lane] = p;
}

// ===== layer2 fused: per-dst softmax (LDS weights) + bf16 gather + bias =====
// pass B: 3 edge-slots x 20 channel-pair lanes, unrolled x2 (6 outstanding gathers)
__global__ __launch_bounds__(256) void agg2_kernel(const int* __restrict__ row,
                                                   const int* __restrict__ csr_src,
                                                   const float* __restrict__ als,
                                                   const float* __restrict__ ald,
                                                   const unsigned short* __restrict__ h2b,
                                                   const float* __restrict__ b2,
                                                   float* __restrict__ out) {
    __shared__ float wbuf[4][MAXD];
    int wv   = threadIdx.x >> 6;
    int lane = threadIdx.x & 63;
    int d    = blockIdx.x * 4 + wv;
    int start = row[d], end = row[d + 1], deg = end - start;
    float aldd = ald[d];

    float mx = NEG_INF;
    for (int j = lane; j < deg; j += 64) {
        int s = csr_src[start + j];
        float a = leaky(als[s] + aldd);
        if (j < MAXD) wbuf[wv][j] = a;
        mx = fmaxf(mx, a);
    }
    #pragma unroll
    for (int off = 32; off >= 1; off >>= 1) mx = fmaxf(mx, __shfl_xor(mx, off));
    __syncthreads();

    float sm = 0.f;
    for (int j = lane; j < deg; j += 64) {
        float a;
        if (j < MAXD) a = wbuf[wv][j];
        else { int s = csr_src[start + j]; a = leaky(als[s] + aldd); }
        float e = __expf(a - mx);
        if (j < MAXD) wbuf[wv][j] = e;
        sm += e;
    }
    #pragma unroll
    for (int off = 32; off >= 1; off >>= 1) sm += __shfl_xor(sm, off);
    __syncthreads();
    float inv = 1.f / (sm + 1e-16f);

    auto wgt = [&](int jj, int ss) -> float {
        if (jj < MAXD) return wbuf[wv][jj];
        return __expf(leaky(als[ss] + aldd) - mx);
    };

    int slot = lane / 20;              // 0..2 active, 3 idle
    int idx  = lane - slot * 20;       // channel pair 0..19
    float acc0 = 0.f, acc1 = 0.f;
    if (lane < 60) {
        int j = slot;
        for (; j + 3 < deg; j += 6) {
            int s0 = csr_src[start + j];
            int s1 = csr_src[start + j + 3];
            unsigned hv0 = *(const unsigned*)(h2b + (size_t)s0 * 40 + 2 * idx);
            unsigned hv1 = *(const unsigned*)(h2b + (size_t)s1 * 40 + 2 * idx);
            float w0 = wgt(j, s0) * inv;
            float w1 = wgt(j + 3, s1) * inv;
            acc0 += __uint_as_float(hv0 << 16) * w0 + __uint_as_float(hv1 << 16) * w1;
            acc1 += __uint_as_float(hv0 & 0xffff0000u) * w0
                  + __uint_as_float(hv1 & 0xffff0000u) * w1;
        }
        for (; j < deg; j += 3) {
            int s0 = csr_src[start + j];
            unsigned hv0 = *(const unsigned*)(h2b + (size_t)s0 * 40 + 2 * idx);
            float w0 = wgt(j, s0) * inv;
            acc0 += __uint_as_float(hv0 << 16)         * w0;
            acc1 += __uint_as_float(hv0 & 0xffff0000u) * w0;
        }
    }
    // reduce across the 3 slots: lanes idx, idx+20, idx+40
    float t0 = __shfl(acc0, idx + 20), u0 = __shfl(acc1, idx + 20);
    float t1 = __shfl(acc0, idx + 40), u1 = __shfl(acc1, idx + 40);
    acc0 += t0 + t1; acc1 += u0 + u1;
    if (lane < 20) {
        float2 o = make_float2(acc0 + b2[2 * lane], acc1 + b2[2 * lane + 1]);
        *(float2*)&out[(size_t)d * 40 + 2 * lane] = o;
    }
}

// ===== GEMM2: h2b[N,40] bf16 = out1b[N,128](bf16) @ W2[128,40]; 64 rows/block =====
__global__ __launch_bounds__(320) void gemm2_kernel(const unsigned short* __restrict__ xb,
                                                    const float* __restrict__ W,
                                                    unsigned short* __restrict__ h2b) {
    __shared__ float wS[128 * 40];    // 20 KB
    __shared__ float xS[64 * 129];    // 33 KB (+1 pad)
    int t = threadIdx.x;
    int row0 = blockIdx.x * 64;
    for (int i = t; i < 128 * 40; i += 320) wS[i] = W[i];
    for (int fi = t; fi < 4096; fi += 320) {          // 64 rows x 64 bf16x2
        int r = fi >> 6, cp2 = fi & 63;
        int gr = row0 + r;
        unsigned v = 0;
        if (gr < N_NODES) v = *(const unsigned*)&xb[(size_t)gr * 128 + 2 * cp2];
        xS[r * 129 + 2 * cp2 + 0] = __uint_as_float(v << 16);
        xS[r * 129 + 2 * cp2 + 1] = __uint_as_float(v & 0xffff0000u);
    }
    __syncthreads();
    int cp = t % 20;        // col pair -> cols {2cp, 2cp+1}
    int rg = t / 20;        // 0..15 -> rows rg*4..rg*4+3
    float acc[4][2] = {{0.f,0.f},{0.f,0.f},{0.f,0.f},{0.f,0.f}};
    for (int k = 0; k < 128; ++k) {
        float2 w2 = *(float2*)&wS[k * 40 + 2 * cp];
        #pragma unroll
        for (int r = 0; r < 4; ++r) {
            float xv = xS[(rg * 4 + r) * 129 + k];
            acc[r][0] += xv * w2.x;
            acc[r][1] += xv * w2.y;
        }
    }
    #pragma unroll
    for (int r = 0; r < 4; ++r) {
        int n = row0 + rg * 4 + r;
        if (n < N_NODES) {
            unsigned p = ((unsigned)f2bf(acc[r][1]) << 16) | f2bf(acc[r][0]);
            *(unsigned*)&h2b[(size_t)n * 40 + 2 * cp] = p;
        }
    }
}

// ================= workspace layout (float-sized slots) =================
constexpr size_t OFF_H1B    = 0;          // h1b bf16 (3.2M slots); h2b overlays after agg1
constexpr size_t OFF_OUT1   = 3200000;    // out1b bf16 (3.2M slots used)
constexpr size_t OFF_ALS1   = 9600000;    // 200,000 (als2 overlays)
constexpr size_t OFF_ALD1   = 9800000;    // 200,000 (ald2 overlays)
constexpr size_t OFF_ROW    = 10000000;   // 50,001 ints
constexpr size_t OFF_CURSOR = 10060000;   // 50,000 ints
constexpr size_t OFF_DEG    = 10120000;   // 50,000 ints
constexpr size_t OFF_PART   = 10180000;   // 128 ints
constexpr size_t OFF_CSRC   = 10200000;   // 850,000 ints
constexpr size_t WS_FLOATS  = 11050000;   // 44.2 MB

extern "C" void kernel_launch(void* const* d_in, const int* in_sizes, int n_in,
                              void* d_out, int out_size, void* d_ws, size_t ws_size,
                              hipStream_t stream) {
    const float* x   = (const float*)d_in[0];
    const int*   ei  = (const int*)  d_in[1];
    const float* W1  = (const float*)d_in[2];
    const float* as1 = (const float*)d_in[3];
    const float* ad1 = (const float*)d_in[4];
    const float* b1  = (const float*)d_in[5];
    const float* W2  = (const float*)d_in[6];
    const float* as2 = (const float*)d_in[7];
    const float* ad2 = (const float*)d_in[8];
    const float* b2  = (const float*)d_in[9];
    float* out = (float*)d_out;

    if (ws_size < WS_FLOATS * sizeof(float)) return;

    float* ws = (float*)d_ws;
    unsigned short* h1b   = (unsigned short*)(ws + OFF_H1B);
    unsigned short* h2b   = (unsigned short*)(ws + OFF_H1B);   // overlay, h1b dead after agg1
    unsigned short* out1b = (unsigned short*)(ws + OFF_OUT1);
    float* als1    = ws + OFF_ALS1;
    float* ald1    = ws + OFF_ALD1;
    float* als2    = ws + OFF_ALS1;   // overlay
    float* ald2    = ws + OFF_ALD1;   // overlay
    int*   rowp    = (int*)(ws + OFF_ROW);
    int*   cursor  = (int*)(ws + OFF_CURSOR);
    int*   deg     = (int*)(ws + OFF_DEG);
    int*   part    = (int*)(ws + OFF_PART);
    int*   csr_src = (int*)(ws + OFF_CSRC);

    int egrid = cdiv(ETOT, 256);

    // ---- CSR build (shared by both layers) ----
    hipMemsetAsync(deg, 0, (size_t)N_NODES * sizeof(int), stream);
    deg_count_kernel<<<egrid, 256, 0, stream>>>(ei, deg);
    partial_sum_kernel<<<SCAN_NBLK, 256, 0, stream>>>(deg, part);
    scan_part_kernel<<<1, 64, 0, stream>>>(part);
    chunk_scan_kernel<<<SCAN_NBLK, 256, 0, stream>>>(deg, part, rowp, cursor);
    fill_csr_kernel<<<egrid, 256, 0, stream>>>(ei, cursor, csr_src);

    // ---- layer 1 ----
    gemm1_kernel<<<cdiv(N_NODES, 32), 256, 0, stream>>>(x, W1, as1, ad1, h1b, als1, ald1);
    agg1_kernel<<<N_NODES / 4, 256, 0, stream>>>(rowp, csr_src,
                                                 (const float4*)als1, (const float4*)ald1,
                                                 h1b, b1, out1b);

    // ---- layer 2 ----
    gemm2_kernel<<<cdiv(N_NODES, 64), 320, 0, stream>>>(out1b, W2, h2b);
    att2_kernel<<<cdiv(N_NODES, 4), 256, 0, stream>>>(h2b, as2, ad2, als2, ald2);
    agg2_kernel<<<N_NODES / 4, 256, 0, stream>>>(rowp, csr_src, als2, ald2, h2b, b2, out);
}

// Round 6
// 359.482 us; speedup vs baseline: 1.0524x; 1.0524x over previous
//
#include <hip/hip_runtime.h>
#include <hip/hip_bf16.h>
#include <math.h>

// Problem constants
constexpr int N_NODES = 50000;
constexpr int E_EDGES = 800000;
constexpr int ETOT    = E_EDGES + N_NODES;   // +self loops
constexpr float NEG_SLOPE = 0.2f;
constexpr float NEG_INF   = -3.0e38f;
constexpr int MAXD = 128;   // LDS-cached edges per dst (fallback beyond)

static inline int cdiv(long long a, int b) { return (int)((a + b - 1) / b); }

__device__ inline float leaky(float a) { return a > 0.f ? a : NEG_SLOPE * a; }
__device__ inline float bf2f(unsigned short u) { return __uint_as_float((unsigned)u << 16); }
__device__ inline unsigned short f2bf(float f) {
    __hip_bfloat16 h = __float2bfloat16(f);
    return *reinterpret_cast<unsigned short*>(&h);
}
__device__ inline void edge_sd(const int* __restrict__ ei, int e, int& s, int& d) {
    if (e < E_EDGES) { s = ei[e]; d = ei[E_EDGES + e]; }
    else             { s = e - E_EDGES; d = s; }
}

// ====== GEMM1 + fused att1: h1b[N,128] bf16, als1/ald1[N,4] ======
// 32 rows/block, 4 rows/thread, k2-blocked (float2 x, 2x float4 w).
// VGPR budget ~110 (k4-float4 variant hit 244 VGPR -> 9% occupancy -> 85us. Don't.)
// 16KB wS chunk + 16KB xS = 32KB LDS -> 5 blocks/CU.
__global__ __launch_bounds__(256) void gemm1_kernel(const float* __restrict__ x,
                                                    const float* __restrict__ W,
                                                    const float* __restrict__ as1,
                                                    const float* __restrict__ ad1,
                                                    unsigned short* __restrict__ h1b,
                                                    float* __restrict__ als,
                                                    float* __restrict__ ald) {
    __shared__ float wS[32 * 128];   // 16 KB (quarter of W at a time)
    __shared__ float xS[32 * 128];   // 16 KB
    int t = threadIdx.x;
    int row0 = blockIdx.x * 32;
    #pragma unroll
    for (int i = 0; i < 4; ++i) {
        int fi = i * 256 + t;
        int r = fi >> 5, c4 = (fi & 31) * 4;
        int gr = row0 + r;
        float4 v = make_float4(0.f, 0.f, 0.f, 0.f);
        if (gr < N_NODES) v = *(const float4*)&x[(size_t)gr * 128 + c4];
        *(float4*)&xS[r * 128 + c4] = v;
    }
    int rg   = t >> 5;          // row group 0..7 -> rows rg*4..rg*4+3
    int col4 = (t & 31) * 4;    // 0..124
    float4 a0 = make_float4(0.f,0.f,0.f,0.f), a1 = a0, a2 = a0, a3 = a0;
    for (int kk = 0; kk < 128; kk += 32) {
        __syncthreads();
        #pragma unroll
        for (int i = 0; i < 4; ++i) {
            int idx = (i * 256 + t) * 4;
            *(float4*)&wS[idx] = *(const float4*)&W[kk * 128 + idx];
        }
        __syncthreads();
        for (int k2 = 0; k2 < 32; k2 += 2) {
            float4 w0 = *(float4*)&wS[(k2 + 0) * 128 + col4];
            float4 w1 = *(float4*)&wS[(k2 + 1) * 128 + col4];
            float2 x0 = *(float2*)&xS[(rg * 4 + 0) * 128 + kk + k2];
            float2 x1 = *(float2*)&xS[(rg * 4 + 1) * 128 + kk + k2];
            float2 x2 = *(float2*)&xS[(rg * 4 + 2) * 128 + kk + k2];
            float2 x3 = *(float2*)&xS[(rg * 4 + 3) * 128 + kk + k2];
            a0.x += x0.x*w0.x + x0.y*w1.x; a0.y += x0.x*w0.y + x0.y*w1.y;
            a0.z += x0.x*w0.z + x0.y*w1.z; a0.w += x0.x*w0.w + x0.y*w1.w;
            a1.x += x1.x*w0.x + x1.y*w1.x; a1.y += x1.x*w0.y + x1.y*w1.y;
            a1.z += x1.x*w0.z + x1.y*w1.z; a1.w += x1.x*w0.w + x1.y*w1.w;
            a2.x += x2.x*w0.x + x2.y*w1.x; a2.y += x2.x*w0.y + x2.y*w1.y;
            a2.z += x2.x*w0.z + x2.y*w1.z; a2.w += x2.x*w0.w + x2.y*w1.w;
            a3.x += x3.x*w0.x + x3.y*w1.x; a3.y += x3.x*w0.y + x3.y*w1.y;
            a3.z += x3.x*w0.z + x3.y*w1.z; a3.w += x3.x*w0.w + x3.y*w1.w;
        }
    }
    float s0 = as1[col4], s1 = as1[col4 + 1], s2 = as1[col4 + 2], s3 = as1[col4 + 3];
    float d0 = ad1[col4], d1 = ad1[col4 + 1], d2 = ad1[col4 + 2], d3 = ad1[col4 + 3];
    #pragma unroll
    for (int r = 0; r < 4; ++r) {
        float4 a = (r == 0) ? a0 : (r == 1) ? a1 : (r == 2) ? a2 : a3;
        int n = row0 + rg * 4 + r;
        float ps = a.x * s0 + a.y * s1 + a.z * s2 + a.w * s3;
        float pd = a.x * d0 + a.y * d1 + a.z * d2 + a.w * d3;
        #pragma unroll
        for (int off = 1; off <= 4; off <<= 1) {
            ps += __shfl_xor(ps, off);
            pd += __shfl_xor(pd, off);
        }
        if (n < N_NODES) {
            uint2 packed;
            packed.x = ((unsigned)f2bf(a.y) << 16) | f2bf(a.x);
            packed.y = ((unsigned)f2bf(a.w) << 16) | f2bf(a.z);
            *(uint2*)&h1b[(size_t)n * 128 + col4] = packed;
            if ((t & 7) == 0) {
                int head = (t & 31) >> 3;
                als[n * 4 + head] = ps;
                ald[n * 4 + head] = pd;
            }
        }
    }
}

// ============ attention logits layer2 (from bf16 h2) ============
__global__ __launch_bounds__(256) void att2_kernel(const unsigned short* __restrict__ h2b,
                                                   const float* __restrict__ as,
                                                   const float* __restrict__ ad,
                                                   float* __restrict__ als,
                                                   float* __restrict__ ald) {
    int t = threadIdx.x;
    int n = blockIdx.x * 4 + (t >> 6);
    if (n >= N_NODES) return;
    int lane = t & 63;
    float v = (lane < 40) ? bf2f(h2b[(size_t)n * 40 + lane]) : 0.f;
    float s = (lane < 40) ? v * as[lane] : 0.f;
    float d = (lane < 40) ? v * ad[lane] : 0.f;
    #pragma unroll
    for (int off = 32; off >= 1; off >>= 1) {
        s += __shfl_xor(s, off);
        d += __shfl_xor(d, off);
    }
    if (lane == 0) { als[n] = s; ald[n] = d; }
}

// ================= CSR build =================
__global__ __launch_bounds__(256) void deg_count_kernel(const int* __restrict__ ei,
                                                        int* __restrict__ deg) {
    int e = blockIdx.x * 256 + threadIdx.x;
    if (e >= ETOT) return;
    int d = (e < E_EDGES) ? ei[E_EDGES + e] : (e - E_EDGES);
    atomicAdd(&deg[d], 1);
}

constexpr int SCAN_CHUNK = 512;
constexpr int SCAN_NBLK  = (N_NODES + SCAN_CHUNK - 1) / SCAN_CHUNK;   // 98

__global__ __launch_bounds__(256) void partial_sum_kernel(const int* __restrict__ deg,
                                                          int* __restrict__ part) {
    __shared__ int s[256];
    int b = blockIdx.x, t = threadIdx.x;
    int i0 = b * SCAN_CHUNK + t;
    int v = 0;
    if (i0 < N_NODES) v += deg[i0];
    if (i0 + 256 < N_NODES && (t + 256) < SCAN_CHUNK) v += deg[i0 + 256];
    s[t] = v; __syncthreads();
    for (int off = 128; off; off >>= 1) {
        if (t < off) s[t] += s[t + off];
        __syncthreads();
    }
    if (t == 0) part[b] = s[0];
}

__global__ void scan_part_kernel(int* __restrict__ part) {
    if (threadIdx.x == 0 && blockIdx.x == 0) {
        int acc = 0;
        for (int i = 0; i < SCAN_NBLK; ++i) { int v = part[i]; part[i] = acc; acc += v; }
    }
}

__global__ __launch_bounds__(256) void chunk_scan_kernel(const int* __restrict__ deg,
                                                         const int* __restrict__ part,
                                                         int* __restrict__ row,
                                                         int* __restrict__ cursor) {
    __shared__ int s[256];
    int b = blockIdx.x, t = threadIdx.x;
    int base = b * SCAN_CHUNK;
    int i0 = base + 2 * t, i1 = base + 2 * t + 1;
    int a0 = (i0 < N_NODES) ? deg[i0] : 0;
    int a1 = (i1 < N_NODES) ? deg[i1] : 0;
    s[t] = a0 + a1;
    __syncthreads();
    for (int off = 1; off < 256; off <<= 1) {
        int v = (t >= off) ? s[t - off] : 0;
        __syncthreads();
        s[t] += v;
        __syncthreads();
    }
    int excl = s[t] - (a0 + a1);
    int off0 = part[b] + excl;
    if (i0 < N_NODES) { row[i0] = off0;      cursor[i0] = off0; }
    if (i1 < N_NODES) { row[i1] = off0 + a0; cursor[i1] = off0 + a0; }
    if (b == 0 && t == 0) row[N_NODES] = ETOT;
}

__global__ __launch_bounds__(256) void fill_csr_kernel(const int* __restrict__ ei,
                                                       int* __restrict__ cursor,
                                                       int* __restrict__ csr_src) {
    int e = blockIdx.x * 256 + threadIdx.x;
    if (e >= ETOT) return;
    int s, d; edge_sd(ei, e, s, d);
    int p = atomicAdd(&cursor[d], 1);
    csr_src[p] = s;
}

// ===== layer1 fused: per-dst softmax (LDS-cached weights) + bf16 gather + bias + ELU =====
// one wave per dst; pass B: lane l <-> channels {2l, 2l+1}, head = l>>4; unrolled x4
__global__ __launch_bounds__(256) void agg1_kernel(const int* __restrict__ row,
                                                   const int* __restrict__ csr_src,
                                                   const float4* __restrict__ als4,
                                                   const float4* __restrict__ ald4,
                                                   const unsigned short* __restrict__ h1b,
                                                   const float* __restrict__ b1,
                                                   unsigned short* __restrict__ out1b) {
    __shared__ float wbuf[4][MAXD * 4] __attribute__((aligned(16)));
    int wv   = threadIdx.x >> 6;
    int lane = threadIdx.x & 63;
    int d    = blockIdx.x * 4 + wv;           // grid exactly covers N
    int start = row[d], end = row[d + 1], deg = end - start;
    float4 aldd = ald4[d];

    // pass A: alpha -> LDS, per-lane max
    float4 mx = make_float4(NEG_INF, NEG_INF, NEG_INF, NEG_INF);
    for (int j = lane; j < deg; j += 64) {
        int s = csr_src[start + j];
        float4 a = als4[s];
        a.x = leaky(a.x + aldd.x); a.y = leaky(a.y + aldd.y);
        a.z = leaky(a.z + aldd.z); a.w = leaky(a.w + aldd.w);
        if (j < MAXD) *(float4*)&wbuf[wv][j * 4] = a;
        mx.x = fmaxf(mx.x, a.x); mx.y = fmaxf(mx.y, a.y);
        mx.z = fmaxf(mx.z, a.z); mx.w = fmaxf(mx.w, a.w);
    }
    #pragma unroll
    for (int off = 32; off >= 1; off >>= 1) {
        mx.x = fmaxf(mx.x, __shfl_xor(mx.x, off));
        mx.y = fmaxf(mx.y, __shfl_xor(mx.y, off));
        mx.z = fmaxf(mx.z, __shfl_xor(mx.z, off));
        mx.w = fmaxf(mx.w, __shfl_xor(mx.w, off));
    }
    __syncthreads();

    // pass A2: exp in LDS, per-lane sum
    float4 sm = make_float4(0.f, 0.f, 0.f, 0.f);
    for (int j = lane; j < deg; j += 64) {
        float4 a;
        if (j < MAXD) a = *(float4*)&wbuf[wv][j * 4];
        else {
            int s = csr_src[start + j];
            float4 t = als4[s];
            a.x = leaky(t.x + aldd.x); a.y = leaky(t.y + aldd.y);
            a.z = leaky(t.z + aldd.z); a.w = leaky(t.w + aldd.w);
        }
        float4 e;
        e.x = __expf(a.x - mx.x); e.y = __expf(a.y - mx.y);
        e.z = __expf(a.z - mx.z); e.w = __expf(a.w - mx.w);
        if (j < MAXD) *(float4*)&wbuf[wv][j * 4] = e;
        sm.x += e.x; sm.y += e.y; sm.z += e.z; sm.w += e.w;
    }
    #pragma unroll
    for (int off = 32; off >= 1; off >>= 1) {
        sm.x += __shfl_xor(sm.x, off);
        sm.y += __shfl_xor(sm.y, off);
        sm.z += __shfl_xor(sm.z, off);
        sm.w += __shfl_xor(sm.w, off);
    }
    __syncthreads();

    int head = lane >> 4;
    float m_h = (head & 2) ? ((head & 1) ? mx.w : mx.z) : ((head & 1) ? mx.y : mx.x);
    float s_h = (head & 2) ? ((head & 1) ? sm.w : sm.z) : ((head & 1) ? sm.y : sm.x);
    float d_h = (head & 2) ? ((head & 1) ? aldd.w : aldd.z) : ((head & 1) ? aldd.y : aldd.x);
    float inv_h = 1.f / (s_h + 1e-16f);

    auto wgt = [&](int jj, int ss) -> float {
        if (jj < MAXD) return wbuf[wv][jj * 4 + head];
        float4 a = als4[ss];
        float ah = (head & 2) ? ((head & 1) ? a.w : a.z) : ((head & 1) ? a.y : a.x);
        return __expf(leaky(ah + d_h) - m_h);
    };

    // pass B: gather-aggregate (bf16 rows, cached weights), unrolled x4 for latency hiding
    float acc0 = 0.f, acc1 = 0.f;
    int j = 0;
    for (; j + 3 < deg; j += 4) {
        int s0 = csr_src[start + j];
        int s1 = csr_src[start + j + 1];
        int s2 = csr_src[start + j + 2];
        int s3 = csr_src[start + j + 3];
        unsigned hv0 = *(const unsigned*)(h1b + ((size_t)s0 << 7) + 2 * lane);
        unsigned hv1 = *(const unsigned*)(h1b + ((size_t)s1 << 7) + 2 * lane);
        unsigned hv2 = *(const unsigned*)(h1b + ((size_t)s2 << 7) + 2 * lane);
        unsigned hv3 = *(const unsigned*)(h1b + ((size_t)s3 << 7) + 2 * lane);
        float w0 = wgt(j, s0) * inv_h;
        float w1 = wgt(j + 1, s1) * inv_h;
        float w2 = wgt(j + 2, s2) * inv_h;
        float w3 = wgt(j + 3, s3) * inv_h;
        acc0 += __uint_as_float(hv0 << 16) * w0 + __uint_as_float(hv1 << 16) * w1
              + __uint_as_float(hv2 << 16) * w2 + __uint_as_float(hv3 << 16) * w3;
        acc1 += __uint_as_float(hv0 & 0xffff0000u) * w0 + __uint_as_float(hv1 & 0xffff0000u) * w1
              + __uint_as_float(hv2 & 0xffff0000u) * w2 + __uint_as_float(hv3 & 0xffff0000u) * w3;
    }
    for (; j < deg; ++j) {
        int s0 = csr_src[start + j];
        unsigned hv0 = *(const unsigned*)(h1b + ((size_t)s0 << 7) + 2 * lane);
        float w0 = wgt(j, s0) * inv_h;
        acc0 += __uint_as_float(hv0 << 16)         * w0;
        acc1 += __uint_as_float(hv0 & 0xffff0000u) * w0;
    }
    float v0 = acc0 + b1[2 * lane];
    float v1 = acc1 + b1[2 * lane + 1];
    v0 = v0 > 0.f ? v0 : __expf(v0) - 1.f;
    v1 = v1 > 0.f ? v1 : __expf(v1) - 1.f;
    unsigned p = ((unsigned)f2bf(v1) << 16) | f2bf(v0);
    *(unsigned*)&out1b[(size_t)d * 128 + 2 * lane] = p;
}

// ===== layer2 fused: per-dst softmax (LDS weights) + bf16 gather + bias =====
// pass B: 3 edge-slots x 20 channel-pair lanes, unrolled x2 (6 outstanding gathers)
__global__ __launch_bounds__(256) void agg2_kernel(const int* __restrict__ row,
                                                   const int* __restrict__ csr_src,
                                                   const float* __restrict__ als,
                                                   const float* __restrict__ ald,
                                                   const unsigned short* __restrict__ h2b,
                                                   const float* __restrict__ b2,
                                                   float* __restrict__ out) {
    __shared__ float wbuf[4][MAXD];
    int wv   = threadIdx.x >> 6;
    int lane = threadIdx.x & 63;
    int d    = blockIdx.x * 4 + wv;
    int start = row[d], end = row[d + 1], deg = end - start;
    float aldd = ald[d];

    float mx = NEG_INF;
    for (int j = lane; j < deg; j += 64) {
        int s = csr_src[start + j];
        float a = leaky(als[s] + aldd);
        if (j < MAXD) wbuf[wv][j] = a;
        mx = fmaxf(mx, a);
    }
    #pragma unroll
    for (int off = 32; off >= 1; off >>= 1) mx = fmaxf(mx, __shfl_xor(mx, off));
    __syncthreads();

    float sm = 0.f;
    for (int j = lane; j < deg; j += 64) {
        float a;
        if (j < MAXD) a = wbuf[wv][j];
        else { int s = csr_src[start + j]; a = leaky(als[s] + aldd); }
        float e = __expf(a - mx);
        if (j < MAXD) wbuf[wv][j] = e;
        sm += e;
    }
    #pragma unroll
    for (int off = 32; off >= 1; off >>= 1) sm += __shfl_xor(sm, off);
    __syncthreads();
    float inv = 1.f / (sm + 1e-16f);

    auto wgt = [&](int jj, int ss) -> float {
        if (jj < MAXD) return wbuf[wv][jj];
        return __expf(leaky(als[ss] + aldd) - mx);
    };

    int slot = lane / 20;              // 0..2 active, 3 idle
    int idx  = lane - slot * 20;       // channel pair 0..19
    float acc0 = 0.f, acc1 = 0.f;
    if (lane < 60) {
        int j = slot;
        for (; j + 3 < deg; j += 6) {
            int s0 = csr_src[start + j];
            int s1 = csr_src[start + j + 3];
            unsigned hv0 = *(const unsigned*)(h2b + (size_t)s0 * 40 + 2 * idx);
            unsigned hv1 = *(const unsigned*)(h2b + (size_t)s1 * 40 + 2 * idx);
            float w0 = wgt(j, s0) * inv;
            float w1 = wgt(j + 3, s1) * inv;
            acc0 += __uint_as_float(hv0 << 16) * w0 + __uint_as_float(hv1 << 16) * w1;
            acc1 += __uint_as_float(hv0 & 0xffff0000u) * w0
                  + __uint_as_float(hv1 & 0xffff0000u) * w1;
        }
        for (; j < deg; j += 3) {
            int s0 = csr_src[start + j];
            unsigned hv0 = *(const unsigned*)(h2b + (size_t)s0 * 40 + 2 * idx);
            float w0 = wgt(j, s0) * inv;
            acc0 += __uint_as_float(hv0 << 16)         * w0;
            acc1 += __uint_as_float(hv0 & 0xffff0000u) * w0;
        }
    }
    // reduce across the 3 slots: lanes idx, idx+20, idx+40
    float t0 = __shfl(acc0, idx + 20), u0 = __shfl(acc1, idx + 20);
    float t1 = __shfl(acc0, idx + 40), u1 = __shfl(acc1, idx + 40);
    acc0 += t0 + t1; acc1 += u0 + u1;
    if (lane < 20) {
        float2 o = make_float2(acc0 + b2[2 * lane], acc1 + b2[2 * lane + 1]);
        *(float2*)&out[(size_t)d * 40 + 2 * lane] = o;
    }
}

// ===== GEMM2: h2b[N,40] bf16 = out1b[N,128](bf16) @ W2[128,40]; 64 rows/block =====
__global__ __launch_bounds__(320) void gemm2_kernel(const unsigned short* __restrict__ xb,
                                                    const float* __restrict__ W,
                                                    unsigned short* __restrict__ h2b) {
    __shared__ float wS[128 * 40];    // 20 KB
    __shared__ float xS[64 * 129];    // 33 KB (+1 pad)
    int t = threadIdx.x;
    int row0 = blockIdx.x * 64;
    for (int i = t; i < 128 * 40; i += 320) wS[i] = W[i];
    for (int fi = t; fi < 4096; fi += 320) {          // 64 rows x 64 bf16x2
        int r = fi >> 6, cp2 = fi & 63;
        int gr = row0 + r;
        unsigned v = 0;
        if (gr < N_NODES) v = *(const unsigned*)&xb[(size_t)gr * 128 + 2 * cp2];
        xS[r * 129 + 2 * cp2 + 0] = __uint_as_float(v << 16);
        xS[r * 129 + 2 * cp2 + 1] = __uint_as_float(v & 0xffff0000u);
    }
    __syncthreads();
    int cp = t % 20;        // col pair -> cols {2cp, 2cp+1}
    int rg = t / 20;        // 0..15 -> rows rg*4..rg*4+3
    float acc[4][2] = {{0.f,0.f},{0.f,0.f},{0.f,0.f},{0.f,0.f}};
    for (int k = 0; k < 128; ++k) {
        float2 w2 = *(float2*)&wS[k * 40 + 2 * cp];
        #pragma unroll
        for (int r = 0; r < 4; ++r) {
            float xv = xS[(rg * 4 + r) * 129 + k];
            acc[r][0] += xv * w2.x;
            acc[r][1] += xv * w2.y;
        }
    }
    #pragma unroll
    for (int r = 0; r < 4; ++r) {
        int n = row0 + rg * 4 + r;
        if (n < N_NODES) {
            unsigned p = ((unsigned)f2bf(acc[r][1]) << 16) | f2bf(acc[r][0]);
            *(unsigned*)&h2b[(size_t)n * 40 + 2 * cp] = p;
        }
    }
}

// ================= workspace layout (float-sized slots) =================
constexpr size_t OFF_H1B    = 0;          // h1b bf16 (3.2M slots); h2b overlays after agg1
constexpr size_t OFF_OUT1   = 3200000;    // out1b bf16 (3.2M slots used)
constexpr size_t OFF_ALS1   = 9600000;    // 200,000 (als2 overlays)
constexpr size_t OFF_ALD1   = 9800000;    // 200,000 (ald2 overlays)
constexpr size_t OFF_ROW    = 10000000;   // 50,001 ints
constexpr size_t OFF_CURSOR = 10060000;   // 50,000 ints
constexpr size_t OFF_DEG    = 10120000;   // 50,000 ints
constexpr size_t OFF_PART   = 10180000;   // 128 ints
constexpr size_t OFF_CSRC   = 10200000;   // 850,000 ints
constexpr size_t WS_FLOATS  = 11050000;   // 44.2 MB

extern "C" void kernel_launch(void* const* d_in, const int* in_sizes, int n_in,
                              void* d_out, int out_size, void* d_ws, size_t ws_size,
                              hipStream_t stream) {
    const float* x   = (const float*)d_in[0];
    const int*   ei  = (const int*)  d_in[1];
    const float* W1  = (const float*)d_in[2];
    const float* as1 = (const float*)d_in[3];
    const float* ad1 = (const float*)d_in[4];
    const float* b1  = (const float*)d_in[5];
    const float* W2  = (const float*)d_in[6];
    const float* as2 = (const float*)d_in[7];
    const float* ad2 = (const float*)d_in[8];
    const float* b2  = (const float*)d_in[9];
    float* out = (float*)d_out;

    if (ws_size < WS_FLOATS * sizeof(float)) return;

    float* ws = (float*)d_ws;
    unsigned short* h1b   = (unsigned short*)(ws + OFF_H1B);
    unsigned short* h2b   = (unsigned short*)(ws + OFF_H1B);   // overlay, h1b dead after agg1
    unsigned short* out1b = (unsigned short*)(ws + OFF_OUT1);
    float* als1    = ws + OFF_ALS1;
    float* ald1    = ws + OFF_ALD1;
    float* als2    = ws + OFF_ALS1;   // overlay
    float* ald2    = ws + OFF_ALD1;   // overlay
    int*   rowp    = (int*)(ws + OFF_ROW);
    int*   cursor  = (int*)(ws + OFF_CURSOR);
    int*   deg     = (int*)(ws + OFF_DEG);
    int*   part    = (int*)(ws + OFF_PART);
    int*   csr_src = (int*)(ws + OFF_CSRC);

    int egrid = cdiv(ETOT, 256);

    // ---- CSR build (shared by both layers) ----
    hipMemsetAsync(deg, 0, (size_t)N_NODES * sizeof(int), stream);
    deg_count_kernel<<<egrid, 256, 0, stream>>>(ei, deg);
    partial_sum_kernel<<<SCAN_NBLK, 256, 0, stream>>>(deg, part);
    scan_part_kernel<<<1, 64, 0, stream>>>(part);
    chunk_scan_kernel<<<SCAN_NBLK, 256, 0, stream>>>(deg, part, rowp, cursor);
    fill_csr_kernel<<<egrid, 256, 0, stream>>>(ei, cursor, csr_src);

    // ---- layer 1 ----
    gemm1_kernel<<<cdiv(N_NODES, 32), 256, 0, stream>>>(x, W1, as1, ad1, h1b, als1, ald1);
    agg1_kernel<<<N_NODES / 4, 256, 0, stream>>>(rowp, csr_src,
                                                 (const float4*)als1, (const float4*)ald1,
                                                 h1b, b1, out1b);

    // ---- layer 2 ----
    gemm2_kernel<<<cdiv(N_NODES, 64), 320, 0, stream>>>(out1b, W2, h2b);
    att2_kernel<<<cdiv(N_NODES, 4), 256, 0, stream>>>(h2b, as2, ad2, als2, ald2);
    agg2_kernel<<<N_NODES / 4, 256, 0, stream>>>(rowp, csr_src, als2, ald2, h2b, b2, out);
}

// Round 7
// 283.493 us; speedup vs baseline: 1.3344x; 1.2680x over previous
//
#include <hip/hip_runtime.h>
#include <hip/hip_bf16.h>
#include <hip/hip_fp16.h>
#include <math.h>

// Problem constants
constexpr int N_NODES = 50000;
constexpr int E_EDGES = 800000;
constexpr int ETOT    = E_EDGES + N_NODES;   // +self loops
constexpr float NEG_SLOPE = 0.2f;
constexpr int MAXD = 128;   // LDS-cached edges per dst (fallback beyond)

typedef _Float16 half8 __attribute__((ext_vector_type(8)));
typedef float    floatx4 __attribute__((ext_vector_type(4)));

static inline int cdiv(long long a, int b) { return (int)((a + b - 1) / b); }

__device__ inline float leaky(float a) { return a > 0.f ? a : NEG_SLOPE * a; }
__device__ inline unsigned pack2h(float a, float b) {
    union { _Float16 h[2]; unsigned u; } p;
    p.h[0] = (_Float16)a; p.h[1] = (_Float16)b; return p.u;
}
__device__ inline float2 unp2h(unsigned u) {
    __half2 hh = *reinterpret_cast<__half2*>(&u);
    return __half22float2(hh);
}
__device__ inline float sel4(const float4& v, int h) {
    float a = (h & 2) ? v.z : v.x;
    float b = (h & 2) ? v.w : v.y;
    return (h & 1) ? b : a;
}
__device__ inline void edge_sd(const int* __restrict__ ei, int e, int& s, int& d) {
    if (e < E_EDGES) { s = ei[e]; d = ei[E_EDGES + e]; }
    else             { s = e - E_EDGES; d = s; }
}

// ====== GEMM1 (MFMA f16) + fused att1: h1h[N,128] f16, als1/ald1[N,4] ======
// 64 rows/block, 4 waves col-split (wave w -> cols w*32..w*32+31), K=128 in 4 steps.
// X cast f32->f16 while staging; W transposed to wtS[n][k] f16 (+8 pad).
__global__ __launch_bounds__(256) void gemm1_kernel(const float* __restrict__ x,
                                                    const float* __restrict__ W,
                                                    const float* __restrict__ as1,
                                                    const float* __restrict__ ad1,
                                                    unsigned short* __restrict__ h1h,
                                                    float* __restrict__ als,
                                                    float* __restrict__ ald) {
    __shared__ _Float16 xS[64 * 136];    // 17.4 KB (also reused for C transpose)
    __shared__ _Float16 wtS[128 * 136];  // 34.8 KB
    __shared__ float asld[128], adld[128];
    int t = threadIdx.x;
    int row0 = blockIdx.x * 64;
    if (t < 128) { asld[t] = as1[t]; adld[t] = ad1[t]; }
    // stage X (f32 -> f16)
    #pragma unroll
    for (int i = 0; i < 8; ++i) {
        int fi = i * 256 + t;            // 0..2047
        int r = fi >> 5, c4 = (fi & 31) * 4;
        int gr = row0 + r;
        float4 v = make_float4(0.f, 0.f, 0.f, 0.f);
        if (gr < N_NODES) v = *(const float4*)&x[(size_t)gr * 128 + c4];
        union { _Float16 h[4]; uint2 u; } pk;
        pk.h[0] = (_Float16)v.x; pk.h[1] = (_Float16)v.y;
        pk.h[2] = (_Float16)v.z; pk.h[3] = (_Float16)v.w;
        *(uint2*)&xS[r * 136 + c4] = pk.u;
    }
    // stage W transposed (f32 -> f16): task (kp, nq) covers rows 2kp,2kp+1 cols nq*4..+3
    #pragma unroll
    for (int i = 0; i < 8; ++i) {
        int fi = i * 256 + t;            // 0..2047
        int kp = fi & 63, nq = fi >> 6;  // kp 0..63, nq 0..31
        float4 va = *(const float4*)&W[(size_t)(2 * kp) * 128 + nq * 4];
        float4 vb = *(const float4*)&W[(size_t)(2 * kp + 1) * 128 + nq * 4];
        *(unsigned*)&wtS[(nq * 4 + 0) * 136 + 2 * kp] = pack2h(va.x, vb.x);
        *(unsigned*)&wtS[(nq * 4 + 1) * 136 + 2 * kp] = pack2h(va.y, vb.y);
        *(unsigned*)&wtS[(nq * 4 + 2) * 136 + 2 * kp] = pack2h(va.z, vb.z);
        *(unsigned*)&wtS[(nq * 4 + 3) * 136 + 2 * kp] = pack2h(va.w, vb.w);
    }
    __syncthreads();

    int w = t >> 6, lane = t & 63, quad = lane >> 4, l16 = lane & 15;
    floatx4 z = {0.f, 0.f, 0.f, 0.f};
    floatx4 c[4][2];
    #pragma unroll
    for (int rt = 0; rt < 4; ++rt) { c[rt][0] = z; c[rt][1] = z; }
    #pragma unroll
    for (int ks = 0; ks < 4; ++ks) {
        int ko = ks * 32 + quad * 8;
        half8 b0 = *(const half8*)&wtS[(w * 32 + l16) * 136 + ko];
        half8 b1 = *(const half8*)&wtS[(w * 32 + 16 + l16) * 136 + ko];
        #pragma unroll
        for (int rt = 0; rt < 4; ++rt) {
            half8 a = *(const half8*)&xS[(rt * 16 + l16) * 136 + ko];
            c[rt][0] = __builtin_amdgcn_mfma_f32_16x16x32_f16(a, b0, c[rt][0], 0, 0, 0);
            c[rt][1] = __builtin_amdgcn_mfma_f32_16x16x32_f16(a, b1, c[rt][1], 0, 0, 0);
        }
    }
    __syncthreads();
    // transpose C into xS as f16 (C layout: row = quad*4+reg, col = l16)
    #pragma unroll
    for (int rt = 0; rt < 4; ++rt)
        #pragma unroll
        for (int ctl = 0; ctl < 2; ++ctl)
            #pragma unroll
            for (int reg = 0; reg < 4; ++reg)
                xS[(rt * 16 + quad * 4 + reg) * 136 + (w * 32 + ctl * 16 + l16)]
                    = (_Float16)c[rt][ctl][reg];
    __syncthreads();
    // epilogue: thread t -> (row r, head hq); store h1 row segment + logits
    int r = t >> 2, hq = t & 3;
    int n = row0 + r;
    if (n < N_NODES) {
        float ps = 0.f, pd = 0.f;
        #pragma unroll
        for (int i = 0; i < 4; ++i) {
            uint4 uv = *(uint4*)&xS[r * 136 + hq * 32 + i * 8];
            *(uint4*)&h1h[(size_t)n * 128 + hq * 32 + i * 8] = uv;
            union { uint4 u; _Float16 h[8]; } cv; cv.u = uv;
            #pragma unroll
            for (int k = 0; k < 8; ++k) {
                float v = (float)cv.h[k];
                ps += v * asld[hq * 32 + i * 8 + k];
                pd += v * adld[hq * 32 + i * 8 + k];
            }
        }
        als[n * 4 + hq] = ps;
        ald[n * 4 + hq] = pd;
    }
}

// ================= CSR build =================
__global__ __launch_bounds__(256) void deg_count_kernel(const int* __restrict__ ei,
                                                        int* __restrict__ deg) {
    int e = blockIdx.x * 256 + threadIdx.x;
    if (e >= ETOT) return;
    int d = (e < E_EDGES) ? ei[E_EDGES + e] : (e - E_EDGES);
    atomicAdd(&deg[d], 1);
}

constexpr int SCAN_CHUNK = 512;
constexpr int SCAN_NBLK  = (N_NODES + SCAN_CHUNK - 1) / SCAN_CHUNK;   // 98

__global__ __launch_bounds__(256) void partial_sum_kernel(const int* __restrict__ deg,
                                                          int* __restrict__ part) {
    __shared__ int s[256];
    int b = blockIdx.x, t = threadIdx.x;
    int i0 = b * SCAN_CHUNK + t;
    int v = 0;
    if (i0 < N_NODES) v += deg[i0];
    if (i0 + 256 < N_NODES && (t + 256) < SCAN_CHUNK) v += deg[i0 + 256];
    s[t] = v; __syncthreads();
    for (int off = 128; off; off >>= 1) {
        if (t < off) s[t] += s[t + off];
        __syncthreads();
    }
    if (t == 0) part[b] = s[0];
}

__global__ void scan_part_kernel(int* __restrict__ part) {
    if (threadIdx.x == 0 && blockIdx.x == 0) {
        int acc = 0;
        for (int i = 0; i < SCAN_NBLK; ++i) { int v = part[i]; part[i] = acc; acc += v; }
    }
}

__global__ __launch_bounds__(256) void chunk_scan_kernel(const int* __restrict__ deg,
                                                         const int* __restrict__ part,
                                                         int* __restrict__ row,
                                                         int* __restrict__ cursor) {
    __shared__ int s[256];
    int b = blockIdx.x, t = threadIdx.x;
    int base = b * SCAN_CHUNK;
    int i0 = base + 2 * t, i1 = base + 2 * t + 1;
    int a0 = (i0 < N_NODES) ? deg[i0] : 0;
    int a1 = (i1 < N_NODES) ? deg[i1] : 0;
    s[t] = a0 + a1;
    __syncthreads();
    for (int off = 1; off < 256; off <<= 1) {
        int v = (t >= off) ? s[t - off] : 0;
        __syncthreads();
        s[t] += v;
        __syncthreads();
    }
    int excl = s[t] - (a0 + a1);
    int off0 = part[b] + excl;
    if (i0 < N_NODES) { row[i0] = off0;      cursor[i0] = off0; }
    if (i1 < N_NODES) { row[i1] = off0 + a0; cursor[i1] = off0 + a0; }
    if (b == 0 && t == 0) row[N_NODES] = ETOT;
}

__global__ __launch_bounds__(256) void fill_csr_kernel(const int* __restrict__ ei,
                                                       int* __restrict__ cursor,
                                                       int* __restrict__ csr_src) {
    int e = blockIdx.x * 256 + threadIdx.x;
    if (e >= ETOT) return;
    int s, d; edge_sd(ei, e, s, d);
    int p = atomicAdd(&cursor[d], 1);
    csr_src[p] = s;
}

// ===== layer1 fused: per-dst softmax (no max pass; exp is safe for |alpha|<~5)
// + f16 gather + bias + ELU. One wave per dst; no __syncthreads (wbuf is per-wave).
__global__ __launch_bounds__(256) void agg1_kernel(const int* __restrict__ row,
                                                   const int* __restrict__ csr_src,
                                                   const float4* __restrict__ als4,
                                                   const float4* __restrict__ ald4,
                                                   const unsigned short* __restrict__ h1h,
                                                   const float* __restrict__ b1,
                                                   unsigned short* __restrict__ out1h) {
    __shared__ float wbuf[4][MAXD * 4] __attribute__((aligned(16)));
    int wv   = threadIdx.x >> 6;
    int lane = threadIdx.x & 63;
    int d    = blockIdx.x * 4 + wv;           // grid exactly covers N
    int start = row[d], end = row[d + 1], deg = end - start;
    float4 aldd = ald4[d];

    // pass A: e = exp(leaky(als+ald)) -> LDS, accumulate sums
    float4 sm = make_float4(0.f, 0.f, 0.f, 0.f);
    for (int j = lane; j < deg; j += 64) {
        int s = csr_src[start + j];
        float4 a = als4[s];
        float4 e;
        e.x = __expf(leaky(a.x + aldd.x)); e.y = __expf(leaky(a.y + aldd.y));
        e.z = __expf(leaky(a.z + aldd.z)); e.w = __expf(leaky(a.w + aldd.w));
        if (j < MAXD) *(float4*)&wbuf[wv][j * 4] = e;
        sm.x += e.x; sm.y += e.y; sm.z += e.z; sm.w += e.w;
    }
    #pragma unroll
    for (int off = 32; off >= 1; off >>= 1) {
        sm.x += __shfl_xor(sm.x, off);
        sm.y += __shfl_xor(sm.y, off);
        sm.z += __shfl_xor(sm.z, off);
        sm.w += __shfl_xor(sm.w, off);
    }

    int head = lane >> 4;
    float s_h = sel4(sm, head);
    float d_h = sel4(aldd, head);
    float inv_h = 1.f / (s_h + 1e-16f);

    auto wgt = [&](int jj, int ss) -> float {
        if (jj < MAXD) return wbuf[wv][jj * 4 + head];
        float4 a = als4[ss];
        return __expf(leaky(sel4(a, head) + d_h));
    };

    // pass B: gather-aggregate (f16 rows), unrolled x8
    float acc0 = 0.f, acc1 = 0.f;
    int j = 0;
    for (; j + 7 < deg; j += 8) {
        int ss[8]; unsigned hv[8]; float ww[8];
        #pragma unroll
        for (int i = 0; i < 8; ++i) ss[i] = csr_src[start + j + i];
        #pragma unroll
        for (int i = 0; i < 8; ++i)
            hv[i] = *(const unsigned*)(h1h + ((size_t)ss[i] << 7) + 2 * lane);
        #pragma unroll
        for (int i = 0; i < 8; ++i) ww[i] = wgt(j + i, ss[i]) * inv_h;
        #pragma unroll
        for (int i = 0; i < 8; ++i) {
            float2 f = unp2h(hv[i]);
            acc0 += f.x * ww[i]; acc1 += f.y * ww[i];
        }
    }
    for (; j < deg; ++j) {
        int s0 = csr_src[start + j];
        unsigned hv0 = *(const unsigned*)(h1h + ((size_t)s0 << 7) + 2 * lane);
        float w0 = wgt(j, s0) * inv_h;
        float2 f = unp2h(hv0);
        acc0 += f.x * w0; acc1 += f.y * w0;
    }
    float v0 = acc0 + b1[2 * lane];
    float v1 = acc1 + b1[2 * lane + 1];
    v0 = v0 > 0.f ? v0 : __expf(v0) - 1.f;
    v1 = v1 > 0.f ? v1 : __expf(v1) - 1.f;
    *(unsigned*)&out1h[(size_t)d * 128 + 2 * lane] = pack2h(v0, v1);
}

// ===== GEMM2 (MFMA f16) + fused att2: h2h[N,40] f16, als2/ald2[N] =====
// 64 rows/block, 4 waves (wave w -> rows w*16..+15), 3 col-tiles (40 cols + 8 discard).
__global__ __launch_bounds__(256) void gemm2_kernel(const unsigned short* __restrict__ out1h,
                                                    const float* __restrict__ W2,
                                                    const float* __restrict__ as2,
                                                    const float* __restrict__ ad2,
                                                    unsigned short* __restrict__ h2h,
                                                    float* __restrict__ als,
                                                    float* __restrict__ ald) {
    __shared__ _Float16 aS[64 * 136];    // staging + C transpose (cols 40..47 discarded)
    __shared__ _Float16 wt2[48 * 136];   // rows 40..47 uninitialized -> only discarded cols
    __shared__ float asld[40], adld[40];
    int t = threadIdx.x;
    int row0 = blockIdx.x * 64;
    if (t < 40) { asld[t] = as2[t]; adld[t] = ad2[t]; }
    // stage A (f16 copy, no conversion)
    #pragma unroll
    for (int i = 0; i < 4; ++i) {
        int fi = i * 256 + t;             // 0..1023
        int r = fi >> 4, s8 = (fi & 15) * 8;
        int gr = row0 + r;
        uint4 v = make_uint4(0u, 0u, 0u, 0u);
        if (gr < N_NODES) v = *(const uint4*)&out1h[(size_t)gr * 128 + s8];
        *(uint4*)&aS[r * 136 + s8] = v;
    }
    // stage W2 transposed (f32 -> f16)
    #pragma unroll
    for (int i = 0; i < 3; ++i) {
        int fi = i * 256 + t;
        if (fi < 640) {
            int kp = fi & 63, nq = fi >> 6;   // kp 0..63, nq 0..9
            float4 va = *(const float4*)&W2[(size_t)(2 * kp) * 40 + nq * 4];
            float4 vb = *(const float4*)&W2[(size_t)(2 * kp + 1) * 40 + nq * 4];
            *(unsigned*)&wt2[(nq * 4 + 0) * 136 + 2 * kp] = pack2h(va.x, vb.x);
            *(unsigned*)&wt2[(nq * 4 + 1) * 136 + 2 * kp] = pack2h(va.y, vb.y);
            *(unsigned*)&wt2[(nq * 4 + 2) * 136 + 2 * kp] = pack2h(va.z, vb.z);
            *(unsigned*)&wt2[(nq * 4 + 3) * 136 + 2 * kp] = pack2h(va.w, vb.w);
        }
    }
    __syncthreads();

    int w = t >> 6, lane = t & 63, quad = lane >> 4, l16 = lane & 15;
    floatx4 z = {0.f, 0.f, 0.f, 0.f};
    floatx4 c0 = z, c1 = z, c2 = z;
    #pragma unroll
    for (int ks = 0; ks < 4; ++ks) {
        int ko = ks * 32 + quad * 8;
        half8 a  = *(const half8*)&aS[(w * 16 + l16) * 136 + ko];
        half8 b0 = *(const half8*)&wt2[(l16) * 136 + ko];
        half8 b1 = *(const half8*)&wt2[(16 + l16) * 136 + ko];
        half8 b2 = *(const half8*)&wt2[(32 + l16) * 136 + ko];
        c0 = __builtin_amdgcn_mfma_f32_16x16x32_f16(a, b0, c0, 0, 0, 0);
        c1 = __builtin_amdgcn_mfma_f32_16x16x32_f16(a, b1, c1, 0, 0, 0);
        c2 = __builtin_amdgcn_mfma_f32_16x16x32_f16(a, b2, c2, 0, 0, 0);
    }
    __syncthreads();
    #pragma unroll
    for (int reg = 0; reg < 4; ++reg) {
        int rr = (w * 16 + quad * 4 + reg) * 136;
        aS[rr + l16]      = (_Float16)c0[reg];
        aS[rr + 16 + l16] = (_Float16)c1[reg];
        aS[rr + 32 + l16] = (_Float16)c2[reg];
    }
    __syncthreads();
    // h2 store: 64 rows x 40 f16 = 320 uint4 tasks
    for (int fi = t; fi < 320; fi += 256) {
        int r = fi / 5, s = fi - r * 5;
        int n = row0 + r;
        if (n < N_NODES) {
            uint4 v = *(uint4*)&aS[r * 136 + s * 8];
            *(uint4*)&h2h[(size_t)n * 40 + s * 8] = v;
        }
    }
    // fused att2 logits: 4 threads per row, 10 cols each, shfl reduce
    int r = t >> 2, q = t & 3;
    int n = row0 + r;
    float ps = 0.f, pd = 0.f;
    #pragma unroll
    for (int i = 0; i < 10; ++i) {
        int cc = q * 10 + i;
        float v = (float)aS[r * 136 + cc];
        ps += v * asld[cc]; pd += v * adld[cc];
    }
    ps += __shfl_xor(ps, 1); ps += __shfl_xor(ps, 2);
    pd += __shfl_xor(pd, 1); pd += __shfl_xor(pd, 2);
    if (q == 0 && n < N_NODES) { als[n] = ps; ald[n] = pd; }
}

// ===== layer2 fused: per-dst softmax (no max) + f16 gather + bias =====
// pass B: 3 edge-slots x 20 channel-pair lanes, unrolled x4 (12 edges/iter)
__global__ __launch_bounds__(256) void agg2_kernel(const int* __restrict__ row,
                                                   const int* __restrict__ csr_src,
                                                   const float* __restrict__ als,
                                                   const float* __restrict__ ald,
                                                   const unsigned short* __restrict__ h2h,
                                                   const float* __restrict__ b2,
                                                   float* __restrict__ out) {
    __shared__ float wbuf[4][MAXD];
    int wv   = threadIdx.x >> 6;
    int lane = threadIdx.x & 63;
    int d    = blockIdx.x * 4 + wv;
    int start = row[d], end = row[d + 1], deg = end - start;
    float aldd = ald[d];

    float sm = 0.f;
    for (int j = lane; j < deg; j += 64) {
        int s = csr_src[start + j];
        float e = __expf(leaky(als[s] + aldd));
        if (j < MAXD) wbuf[wv][j] = e;
        sm += e;
    }
    #pragma unroll
    for (int off = 32; off >= 1; off >>= 1) sm += __shfl_xor(sm, off);
    float inv = 1.f / (sm + 1e-16f);

    auto wgt = [&](int jj, int ss) -> float {
        if (jj < MAXD) return wbuf[wv][jj];
        return __expf(leaky(als[ss] + aldd));
    };

    int slot = lane / 20;              // 0..2 active, 3 idle
    int idx  = lane - slot * 20;       // channel pair 0..19
    float acc0 = 0.f, acc1 = 0.f;
    if (lane < 60) {
        int j = slot;
        for (; j + 9 < deg; j += 12) {
            int ss[4]; unsigned hv[4]; float ww[4];
            #pragma unroll
            for (int i = 0; i < 4; ++i) ss[i] = csr_src[start + j + 3 * i];
            #pragma unroll
            for (int i = 0; i < 4; ++i)
                hv[i] = *(const unsigned*)(h2h + (size_t)ss[i] * 40 + 2 * idx);
            #pragma unroll
            for (int i = 0; i < 4; ++i) ww[i] = wgt(j + 3 * i, ss[i]) * inv;
            #pragma unroll
            for (int i = 0; i < 4; ++i) {
                float2 f = unp2h(hv[i]);
                acc0 += f.x * ww[i]; acc1 += f.y * ww[i];
            }
        }
        for (; j < deg; j += 3) {
            int s0 = csr_src[start + j];
            unsigned hv0 = *(const unsigned*)(h2h + (size_t)s0 * 40 + 2 * idx);
            float w0 = wgt(j, s0) * inv;
            float2 f = unp2h(hv0);
            acc0 += f.x * w0; acc1 += f.y * w0;
        }
    }
    float t0 = __shfl(acc0, idx + 20), u0 = __shfl(acc1, idx + 20);
    float t1 = __shfl(acc0, idx + 40), u1 = __shfl(acc1, idx + 40);
    acc0 += t0 + t1; acc1 += u0 + u1;
    if (lane < 20) {
        float2 o = make_float2(acc0 + b2[2 * lane], acc1 + b2[2 * lane + 1]);
        *(float2*)&out[(size_t)d * 40 + 2 * lane] = o;
    }
}

// ================= workspace layout (float-sized slots) =================
constexpr size_t OFF_H1H    = 0;          // h1 f16 (3.2M slots); h2 overlays after agg1
constexpr size_t OFF_OUT1   = 3200000;    // out1 f16 (3.2M slots used)
constexpr size_t OFF_ALS1   = 9600000;    // 200,000 (als2 overlays)
constexpr size_t OFF_ALD1   = 9800000;    // 200,000 (ald2 overlays)
constexpr size_t OFF_ROW    = 10000000;   // 50,001 ints
constexpr size_t OFF_CURSOR = 10060000;   // 50,000 ints
constexpr size_t OFF_DEG    = 10120000;   // 50,000 ints
constexpr size_t OFF_PART   = 10180000;   // 128 ints
constexpr size_t OFF_CSRC   = 10200000;   // 850,000 ints
constexpr size_t WS_FLOATS  = 11050000;   // 44.2 MB

extern "C" void kernel_launch(void* const* d_in, const int* in_sizes, int n_in,
                              void* d_out, int out_size, void* d_ws, size_t ws_size,
                              hipStream_t stream) {
    const float* x   = (const float*)d_in[0];
    const int*   ei  = (const int*)  d_in[1];
    const float* W1  = (const float*)d_in[2];
    const float* as1 = (const float*)d_in[3];
    const float* ad1 = (const float*)d_in[4];
    const float* b1  = (const float*)d_in[5];
    const float* W2  = (const float*)d_in[6];
    const float* as2 = (const float*)d_in[7];
    const float* ad2 = (const float*)d_in[8];
    const float* b2  = (const float*)d_in[9];
    float* out = (float*)d_out;

    if (ws_size < WS_FLOATS * sizeof(float)) return;

    float* ws = (float*)d_ws;
    unsigned short* h1h   = (unsigned short*)(ws + OFF_H1H);
    unsigned short* h2h   = (unsigned short*)(ws + OFF_H1H);   // overlay, h1 dead after agg1
    unsigned short* out1h = (unsigned short*)(ws + OFF_OUT1);
    float* als1    = ws + OFF_ALS1;
    float* ald1    = ws + OFF_ALD1;
    float* als2    = ws + OFF_ALS1;   // overlay, dead after agg1
    float* ald2    = ws + OFF_ALD1;   // overlay
    int*   rowp    = (int*)(ws + OFF_ROW);
    int*   cursor  = (int*)(ws + OFF_CURSOR);
    int*   deg     = (int*)(ws + OFF_DEG);
    int*   part    = (int*)(ws + OFF_PART);
    int*   csr_src = (int*)(ws + OFF_CSRC);

    int egrid = cdiv(ETOT, 256);

    // ---- CSR build (shared by both layers) ----
    hipMemsetAsync(deg, 0, (size_t)N_NODES * sizeof(int), stream);
    deg_count_kernel<<<egrid, 256, 0, stream>>>(ei, deg);
    partial_sum_kernel<<<SCAN_NBLK, 256, 0, stream>>>(deg, part);
    scan_part_kernel<<<1, 64, 0, stream>>>(part);
    chunk_scan_kernel<<<SCAN_NBLK, 256, 0, stream>>>(deg, part, rowp, cursor);
    fill_csr_kernel<<<egrid, 256, 0, stream>>>(ei, cursor, csr_src);

    // ---- layer 1 ----
    gemm1_kernel<<<cdiv(N_NODES, 64), 256, 0, stream>>>(x, W1, as1, ad1, h1h, als1, ald1);
    agg1_kernel<<<N_NODES / 4, 256, 0, stream>>>(rowp, csr_src,
                                                 (const float4*)als1, (const float4*)ald1,
                                                 h1h, b1, out1h);

    // ---- layer 2 ----
    gemm2_kernel<<<cdiv(N_NODES, 64), 256, 0, stream>>>(out1h, W2, as2, ad2, h2h, als2, ald2);
    agg2_kernel<<<N_NODES / 4, 256, 0, stream>>>(rowp, csr_src, als2, ald2, h2h, b2, out);
}